// Round 1
// baseline (156.195 us; speedup 1.0000x reference)
//
#include <hip/hip_runtime.h>
#include <math.h>

#define NQ    13
#define DIM   8192      // 2^13
#define NL    2
#define BLOCK 256

__global__ __launch_bounds__(BLOCK, 1) void qsim_kernel(
    const float* __restrict__ x,
    const float* __restrict__ w,
    float* __restrict__ out)
{
    __shared__ float re[DIM];
    __shared__ float im[DIM];
    __shared__ float red[BLOCK / 64];

    const int b   = blockIdx.x;
    const int tid = threadIdx.x;
    const float* xb = x + (size_t)b * DIM;

    // ---- load state (unnormalized) + sum of squares ----
    float ss = 0.f;
    for (int i = tid; i < DIM; i += BLOCK) {
        float v = xb[i];
        re[i] = v;
        im[i] = 0.f;
        ss += v * v;
    }
    // wave (64-lane) reduce, then cross-wave via LDS
    #pragma unroll
    for (int off = 32; off > 0; off >>= 1) ss += __shfl_down(ss, off, 64);
    if ((tid & 63) == 0) red[tid >> 6] = ss;
    __syncthreads();
    const float total = red[0] + red[1] + red[2] + red[3];  // = ||x||^2, preserved by unitaries
    // (no normalize pass: divide at the end)

    // ---- circuit ----
    for (int l = 0; l < NL; ++l) {
        const int r = (l % (NQ - 1)) + 1;

        // 13 Rot gates
        for (int q = 0; q < NQ; ++q) {
            const float phi   = w[(l * NQ + q) * 3 + 0];
            const float theta = w[(l * NQ + q) * 3 + 1];
            const float omega = w[(l * NQ + q) * 3 + 2];
            float c, s;
            sincosf(theta * 0.5f, &s, &c);
            float sps, cps, sds, cds;
            sincosf(0.5f * (phi + omega), &sps, &cps);
            sincosf(0.5f * (phi - omega), &sds, &cds);
            // U = [[e^{-i(p+o)/2} c, -e^{+i(p-o)/2} s],
            //      [e^{-i(p-o)/2} s,  e^{+i(p+o)/2} c]]
            const float u00r =  cps * c, u00i = -sps * c;
            const float u01r = -cds * s, u01i = -sds * s;
            const float u10r =  cds * s, u10i = -sds * s;
            const float u11r =  cps * c, u11i =  sps * c;

            const int bp     = NQ - 1 - q;    // bit position of qubit q
            const int stride = 1 << bp;

            __syncthreads();   // previous pass fully written
            for (int p = tid; p < DIM / 2; p += BLOCK) {
                const int i0 = ((p >> bp) << (bp + 1)) | (p & (stride - 1));
                const int i1 = i0 | stride;
                const float a0r = re[i0], a0i = im[i0];
                const float a1r = re[i1], a1i = im[i1];
                re[i0] = u00r * a0r - u00i * a0i + u01r * a1r - u01i * a1i;
                im[i0] = u00r * a0i + u00i * a0r + u01r * a1i + u01i * a1r;
                re[i1] = u10r * a0r - u10i * a0i + u11r * a1r - u11i * a1i;
                im[i1] = u10r * a0i + u10i * a0r + u11r * a1i + u11i * a1r;
            }
        }

        // 13 CNOTs: control cq, target (cq + r) % NQ
        for (int cq = 0; cq < NQ; ++cq) {
            const int tq = (cq + r) % NQ;
            const int cb = NQ - 1 - cq;
            const int tb = NQ - 1 - tq;
            const int hi = cb > tb ? cb : tb;
            const int lo = cb > tb ? tb : cb;

            __syncthreads();
            for (int k = tid; k < DIM / 4; k += BLOCK) {
                // insert 0-bits at positions lo then hi
                const int t1 = ((k  >> lo) << (lo + 1)) | (k  & ((1 << lo) - 1));
                const int t2 = ((t1 >> hi) << (hi + 1)) | (t1 & ((1 << hi) - 1));
                const int i0 = t2 | (1 << cb);      // control=1, target=0
                const int i1 = i0 | (1 << tb);      // control=1, target=1
                const float tr = re[i0], ti = im[i0];
                re[i0] = re[i1]; im[i0] = im[i1];
                re[i1] = tr;     im[i1] = ti;
            }
        }
    }

    // ---- expval(PauliZ(qubit 6)) : bit position 12-6 = 6 ----
    __syncthreads();
    float acc = 0.f;
    for (int i = tid; i < DIM; i += BLOCK) {
        const float pr = re[i] * re[i] + im[i] * im[i];
        acc += ((i >> 6) & 1) ? -pr : pr;
    }
    #pragma unroll
    for (int off = 32; off > 0; off >>= 1) acc += __shfl_down(acc, off, 64);
    __syncthreads();               // red[] safe to reuse
    if ((tid & 63) == 0) red[tid >> 6] = acc;
    __syncthreads();
    if (tid == 0) {
        const float tot = red[0] + red[1] + red[2] + red[3];
        out[b] = tot / total;
    }
}

extern "C" void kernel_launch(void* const* d_in, const int* in_sizes, int n_in,
                              void* d_out, int out_size, void* d_ws, size_t ws_size,
                              hipStream_t stream) {
    const float* x = (const float*)d_in[0];   // (512, 8192) fp32
    const float* w = (const float*)d_in[1];   // (2, 13, 3) fp32
    float* out = (float*)d_out;               // (512,) fp32
    const int B = in_sizes[0] / DIM;
    qsim_kernel<<<B, BLOCK, 0, stream>>>(x, w, out);
}

// Round 2
// 88.969 us; speedup vs baseline: 1.7556x; 1.7556x over previous
//
#include <hip/hip_runtime.h>
#include <math.h>

#define NQ    13
#define DIM   8192
#define BLOCK 256
#define NGATE 26          // 2 layers x 13 Rot gates

// Padded LDS layout: word address = i + 4*(i>>5)  (4 pad words per 32)
// -> pass A (bits 0-4 local) and pass C (granules of 4) are 16B-aligned b128
//    with balanced banks; pass B scalar reads hit distinct banks.
#define SW_PAD(i) ((i) + (((i) >> 5) << 2))
#define LDS_N (DIM + 4 * (DIM / 32))   // 9216 words

// ---- CNOT-chain permutation (GF(2)-linear), folded to compile-time ----
struct PCols { int c[NQ]; };
constexpr PCols make_cols(int r) {
    PCols P{};
    for (int b = 0; b < NQ; ++b) {
        int cc = 1 << b;
        for (int cq = 0; cq < NQ; ++cq) {
            const int cb = 12 - cq;
            const int tb = 12 - ((cq + r) % NQ);
            cc ^= ((cc >> cb) & 1) << tb;
        }
        P.c[b] = cc;
    }
    return P;
}
constexpr PCols C1 = make_cols(1);   // layer 0, r=1
constexpr PCols C2 = make_cols(2);   // layer 1, r=2
constexpr int make_rm6() {           // row 6 of layer-1 permutation matrix
    int m = 0;
    for (int b = 0; b < NQ; ++b) m |= ((make_cols(2).c[b] >> 6) & 1) << b;
    return m;
}
constexpr int RM6 = make_rm6();

// ---- one Rot gate on a 32-amp register subcube, pair bit = local pos P ----
template<int P>
__device__ __forceinline__ void rot32(float* vr, float* vi, const float* __restrict__ g) {
    const float u00r = g[0], u00i = g[1], u01r = g[2], u01i = g[3];
    const float u10r = g[4], u10i = g[5], u11r = g[6], u11i = g[7];
    #pragma unroll
    for (int m = 0; m < 16; ++m) {
        const int j0 = ((m >> P) << (P + 1)) | (m & ((1 << P) - 1));
        const int j1 = j0 | (1 << P);
        const float a0r = vr[j0], a0i = vi[j0];
        const float a1r = vr[j1], a1i = vi[j1];
        vr[j0] = u00r * a0r - u00i * a0i + u01r * a1r - u01i * a1i;
        vi[j0] = u00r * a0i + u00i * a0r + u01r * a1i + u01i * a1r;
        vr[j1] = u10r * a0r - u10i * a0i + u11r * a1r - u11i * a1i;
        vi[j1] = u10r * a0i + u10i * a0r + u11r * a1i + u11i * a1r;
    }
}

__device__ __forceinline__ void lds_load8x4(const float* arr, int base, int step, float* v) {
    #pragma unroll
    for (int g = 0; g < 8; ++g) {
        const float4 t = *(const float4*)&arr[base + step * g];
        v[4*g+0] = t.x; v[4*g+1] = t.y; v[4*g+2] = t.z; v[4*g+3] = t.w;
    }
}
__device__ __forceinline__ void lds_store8x4(float* arr, int base, int step, const float* v) {
    #pragma unroll
    for (int g = 0; g < 8; ++g) {
        float4 t;
        t.x = v[4*g+0]; t.y = v[4*g+1]; t.z = v[4*g+2]; t.w = v[4*g+3];
        *(float4*)&arr[base + step * g] = t;
    }
}

__global__ __launch_bounds__(BLOCK, 1) void qsim_kernel(
    const float* __restrict__ x,
    const float* __restrict__ w,
    float* __restrict__ out)
{
    __shared__ float re[LDS_N];
    __shared__ float im[LDS_N];
    __shared__ float gm[NGATE * 8];
    __shared__ float red[BLOCK / 64];

    const int b   = blockIdx.x;
    const int tid = threadIdx.x;

    // ---- gate matrices: 26 threads, once per block ----
    if (tid < NGATE) {
        const float phi   = w[tid * 3 + 0];
        const float theta = w[tid * 3 + 1];
        const float omega = w[tid * 3 + 2];
        float c, s;  sincosf(0.5f * theta, &s, &c);
        float sps, cps, sds, cds;
        sincosf(0.5f * (phi + omega), &sps, &cps);
        sincosf(0.5f * (phi - omega), &sds, &cds);
        float* g = &gm[tid * 8];
        g[0] =  cps * c;  g[1] = -sps * c;   // u00
        g[2] = -cds * s;  g[3] = -sds * s;   // u01
        g[4] =  cds * s;  g[5] = -sds * s;   // u10
        g[6] =  cps * c;  g[7] =  sps * c;   // u11
    }

    // ---- P0: coalesced global -> LDS (swizzled), sum of squares ----
    const float4* x4 = (const float4*)(x + (size_t)b * DIM);
    float ss = 0.f;
    #pragma unroll
    for (int k = 0; k < 8; ++k) {
        const int m = tid + BLOCK * k;       // float4 index
        const int a = SW_PAD(m * 4);         // multiple of 4 words -> 16B aligned
        const float4 v = x4[m];
        *(float4*)&re[a] = v;
        *(float4*)&im[a] = make_float4(0.f, 0.f, 0.f, 0.f);
        ss += v.x * v.x + v.y * v.y + v.z * v.z + v.w * v.w;
    }
    #pragma unroll
    for (int off = 32; off > 0; off >>= 1) ss += __shfl_down(ss, off, 64);
    if ((tid & 63) == 0) red[tid >> 6] = ss;
    __syncthreads();
    const float total = red[0] + red[1] + red[2] + red[3];  // ||x||^2, invariant

    float vr[32], vi[32];
    const int baseA = 36 * tid;                       // pass A: i = 32t + j
    const int baseB = (tid >> 5) * 1152 + (tid & 31); // pass B: i = hi<<10 | j<<5 | lo
    const int baseC = 4 * tid + 4 * (tid >> 3);       // pass C: i = jh<<10 | t<<2 | jl

    // ================= layer 0 =================
    // P1: bits 0-4  (qubits 12..8)
    lds_load8x4(re, baseA, 4, vr);  lds_load8x4(im, baseA, 4, vi);
    rot32<0>(vr, vi, &gm[(0*13+12)*8]);
    rot32<1>(vr, vi, &gm[(0*13+11)*8]);
    rot32<2>(vr, vi, &gm[(0*13+10)*8]);
    rot32<3>(vr, vi, &gm[(0*13+ 9)*8]);
    rot32<4>(vr, vi, &gm[(0*13+ 8)*8]);
    lds_store8x4(re, baseA, 4, vr); lds_store8x4(im, baseA, 4, vi);
    __syncthreads();

    // P2: bits 5-9  (qubits 7..3)
    #pragma unroll
    for (int j = 0; j < 32; ++j) { vr[j] = re[baseB + 36*j]; vi[j] = im[baseB + 36*j]; }
    rot32<0>(vr, vi, &gm[(0*13+7)*8]);
    rot32<1>(vr, vi, &gm[(0*13+6)*8]);
    rot32<2>(vr, vi, &gm[(0*13+5)*8]);
    rot32<3>(vr, vi, &gm[(0*13+4)*8]);
    rot32<4>(vr, vi, &gm[(0*13+3)*8]);
    #pragma unroll
    for (int j = 0; j < 32; ++j) { re[baseB + 36*j] = vr[j]; im[baseB + 36*j] = vi[j]; }
    __syncthreads();

    // P3: bits 10-12 (qubits 2..0), then all 13 CNOTs as one linear scatter
    lds_load8x4(re, baseC, 1152, vr);  lds_load8x4(im, baseC, 1152, vi);
    rot32<2>(vr, vi, &gm[(0*13+2)*8]);
    rot32<3>(vr, vi, &gm[(0*13+1)*8]);
    rot32<4>(vr, vi, &gm[(0*13+0)*8]);
    __syncthreads();                       // all reads of old state done
    {
        int tbase = 0;                     // i bits 2..9 come from tid bits 0..7
        #pragma unroll
        for (int bb = 2; bb < 10; ++bb) if ((tid >> (bb - 2)) & 1) tbase ^= C1.c[bb];
        #pragma unroll
        for (int j = 0; j < 32; ++j) {     // j = jh<<2|jl : bits {0,1,10,11,12}
            int dest = tbase;
            if (j & 1)  dest ^= C1.c[0];
            if (j & 2)  dest ^= C1.c[1];
            if (j & 4)  dest ^= C1.c[10];
            if (j & 8)  dest ^= C1.c[11];
            if (j & 16) dest ^= C1.c[12];
            const int a = SW_PAD(dest);
            re[a] = vr[j]; im[a] = vi[j];
        }
    }
    __syncthreads();

    // ================= layer 1 =================
    // P4: bits 0-4  (qubits 12..8)
    lds_load8x4(re, baseA, 4, vr);  lds_load8x4(im, baseA, 4, vi);
    rot32<0>(vr, vi, &gm[(1*13+12)*8]);
    rot32<1>(vr, vi, &gm[(1*13+11)*8]);
    rot32<2>(vr, vi, &gm[(1*13+10)*8]);
    rot32<3>(vr, vi, &gm[(1*13+ 9)*8]);
    rot32<4>(vr, vi, &gm[(1*13+ 8)*8]);
    lds_store8x4(re, baseA, 4, vr); lds_store8x4(im, baseA, 4, vi);
    __syncthreads();

    // P5: bits 5-9  (qubits 7..3)
    #pragma unroll
    for (int j = 0; j < 32; ++j) { vr[j] = re[baseB + 36*j]; vi[j] = im[baseB + 36*j]; }
    rot32<0>(vr, vi, &gm[(1*13+7)*8]);
    rot32<1>(vr, vi, &gm[(1*13+6)*8]);
    rot32<2>(vr, vi, &gm[(1*13+5)*8]);
    rot32<3>(vr, vi, &gm[(1*13+4)*8]);
    rot32<4>(vr, vi, &gm[(1*13+3)*8]);
    #pragma unroll
    for (int j = 0; j < 32; ++j) { re[baseB + 36*j] = vr[j]; im[baseB + 36*j] = vi[j]; }
    __syncthreads();

    // P6: bits 10-12 (qubits 2..0); CNOT chain + PauliZ(q6) folded into the
    // sign: bit6 of final index = popc(i & RM6) & 1. No final write needed.
    lds_load8x4(re, baseC, 1152, vr);  lds_load8x4(im, baseC, 1152, vi);
    rot32<2>(vr, vi, &gm[(1*13+2)*8]);
    rot32<3>(vr, vi, &gm[(1*13+1)*8]);
    rot32<4>(vr, vi, &gm[(1*13+0)*8]);

    float acc = 0.f;
    #pragma unroll
    for (int jh = 0; jh < 8; ++jh) {
        #pragma unroll
        for (int jl = 0; jl < 4; ++jl) {
            const int j = jh * 4 + jl;
            const int i = (jh << 10) | (tid << 2) | jl;
            const float pr = vr[j] * vr[j] + vi[j] * vi[j];
            acc += (__popc(i & RM6) & 1) ? -pr : pr;
        }
    }
    #pragma unroll
    for (int off = 32; off > 0; off >>= 1) acc += __shfl_down(acc, off, 64);
    __syncthreads();
    if ((tid & 63) == 0) red[tid >> 6] = acc;
    __syncthreads();
    if (tid == 0) out[b] = (red[0] + red[1] + red[2] + red[3]) / total;
}

extern "C" void kernel_launch(void* const* d_in, const int* in_sizes, int n_in,
                              void* d_out, int out_size, void* d_ws, size_t ws_size,
                              hipStream_t stream) {
    const float* x = (const float*)d_in[0];   // (512, 8192) fp32
    const float* w = (const float*)d_in[1];   // (2, 13, 3) fp32
    float* out = (float*)d_out;               // (512,) fp32
    const int B = in_sizes[0] / DIM;
    qsim_kernel<<<B, BLOCK, 0, stream>>>(x, w, out);
}